// Round 4
// baseline (894.440 us; speedup 1.0000x reference)
//
#include <hip/hip_runtime.h>
#include <cstddef>

#define B_ 64
#define T_ 256
#define C_ 2048
#define H_ 512
#define O_ 11
#define THRESH 1.0f
#define LEAK_ 0.003f
#define OLEAK_ 0.0015f

typedef float v2f __attribute__((ext_vector_type(2)));

// ---------------------------------------------------------------------------
// Kernel 1: transpose w_rec (H x H) -> w_recT (coalesced recurrent gather).
// ---------------------------------------------------------------------------
__global__ __launch_bounds__(256) void transpose_wrec(const float* __restrict__ w,
                                                      float* __restrict__ wt) {
    __shared__ float tile[32][33];
    int tx = threadIdx.x, ty = threadIdx.y;           // block (32, 8)
    int x = blockIdx.x * 32 + tx;
    int y = blockIdx.y * 32 + ty;
#pragma unroll
    for (int i = 0; i < 32; i += 8)
        tile[ty + i][tx] = w[(size_t)(y + i) * H_ + x];
    __syncthreads();
    int x2 = blockIdx.y * 32 + tx;
    int y2 = blockIdx.x * 32 + ty;
#pragma unroll
    for (int i = 0; i < 32; i += 8)
        wt[(size_t)(y2 + i) * H_ + x2] = tile[tx][ty + i];
}

// ---------------------------------------------------------------------------
// Kernel 2: split-K GEMM  P[s] = X @ w1^T.
// BM=128 x BN=128, BK=16, 128 threads, TM=16 x TN=8 microtile
// (2.67 FLOP/LDS-byte -> below LDS-BW ceiling). Software-pipelined:
// global loads for tile k+1 issue BEFORE compute of tile k, so HBM latency
// hides under ~2000 cyc of FMAs and the pre-barrier vmcnt drain is free.
// Fragments read as b128 from bank-disjoint addresses (conflict-free).
// ---------------------------------------------------------------------------
#define BM 128
#define BN 128
#define BK 16

template <int S>
__global__ __launch_bounds__(128, 2) void gemm_ff(const float* __restrict__ A,
                                                  const float* __restrict__ Bw,
                                                  float* __restrict__ Pout) {
    const int K = C_;
    const int N = H_;
    const int kLen  = C_ / S;
    const int kBase = blockIdx.z * kLen;

    __shared__ float As[BK][BM + 4];
    __shared__ float Bs[BK][BN + 4];

    const int t  = threadIdx.x;
    const int tx = t & 15;        // n-dir: 16 x TN=8 -> 128
    const int ty = t >> 4;        // m-dir:  8 x TM=16 -> 128
    const int lr = t >> 2;        // load row 0..31
    const int lc = (t & 3) * 4;   // load col 0,4,8,12

    const float* Ap = A  + (size_t)(blockIdx.y * BM + lr) * K + kBase + lc;
    const float* Bp = Bw + (size_t)(blockIdx.x * BN + lr) * K + kBase + lc;

    float4 ar[4], br[4];
#pragma unroll
    for (int q = 0; q < 4; ++q) {
        ar[q] = *(const float4*)(Ap + (size_t)(q * 32) * K);
        br[q] = *(const float4*)(Bp + (size_t)(q * 32) * K);
    }
    Ap += BK; Bp += BK;

    v2f acc[16][4];
#pragma unroll
    for (int i = 0; i < 16; ++i)
#pragma unroll
        for (int j = 0; j < 4; ++j) acc[i][j] = (v2f){0.f, 0.f};

    const int nT = kLen / BK;
    for (int kt = 0; kt < nT; ++kt) {
        __syncthreads();
#pragma unroll
        for (int q = 0; q < 4; ++q) {
            As[lc + 0][lr + q * 32] = ar[q].x; As[lc + 1][lr + q * 32] = ar[q].y;
            As[lc + 2][lr + q * 32] = ar[q].z; As[lc + 3][lr + q * 32] = ar[q].w;
            Bs[lc + 0][lr + q * 32] = br[q].x; Bs[lc + 1][lr + q * 32] = br[q].y;
            Bs[lc + 2][lr + q * 32] = br[q].z; Bs[lc + 3][lr + q * 32] = br[q].w;
        }
        __syncthreads();

        if (kt + 1 < nT) {       // prefetch next tile; latency hides under FMAs
#pragma unroll
            for (int q = 0; q < 4; ++q) {
                ar[q] = *(const float4*)(Ap + (size_t)(q * 32) * K);
                br[q] = *(const float4*)(Bp + (size_t)(q * 32) * K);
            }
            Ap += BK; Bp += BK;
        }

#pragma unroll
        for (int k = 0; k < BK; ++k) {
            float4 a0 = *(const float4*)&As[k][ty * 8];
            float4 a1 = *(const float4*)&As[k][ty * 8 + 4];
            float4 a2 = *(const float4*)&As[k][64 + ty * 8];
            float4 a3 = *(const float4*)&As[k][64 + ty * 8 + 4];
            float4 bq0 = *(const float4*)&Bs[k][tx * 4];
            float4 bq1 = *(const float4*)&Bs[k][64 + tx * 4];
            v2f b0v = {bq0.x, bq0.y}, b1v = {bq0.z, bq0.w};
            v2f b2v = {bq1.x, bq1.y}, b3v = {bq1.z, bq1.w};
            float av[16] = {a0.x, a0.y, a0.z, a0.w, a1.x, a1.y, a1.z, a1.w,
                            a2.x, a2.y, a2.z, a2.w, a3.x, a3.y, a3.z, a3.w};
#pragma unroll
            for (int i = 0; i < 16; ++i) {
                v2f ai = {av[i], av[i]};
                acc[i][0] += ai * b0v;
                acc[i][1] += ai * b1v;
                acc[i][2] += ai * b2v;
                acc[i][3] += ai * b3v;
            }
        }
    }

    float* P = Pout + (size_t)blockIdx.z * ((size_t)B_ * T_ * H_);
#pragma unroll
    for (int i = 0; i < 16; ++i) {
        int row = blockIdx.y * BM + (i < 8 ? ty * 8 + i : 64 + ty * 8 + (i - 8));
        float* Cp = P + (size_t)row * N + blockIdx.x * BN;
        float4 c0 = {acc[i][0].x, acc[i][0].y, acc[i][1].x, acc[i][1].y};
        float4 c1 = {acc[i][2].x, acc[i][2].y, acc[i][3].x, acc[i][3].y};
        *(float4*)(Cp + tx * 4)      = c0;
        *(float4*)(Cp + 64 + tx * 4) = c1;
    }
}

// ---------------------------------------------------------------------------
// Kernel 2b: in-place split-K reduce: P0 += P1 + ... (ascending s).
// ---------------------------------------------------------------------------
template <int S>
__global__ __launch_bounds__(256) void reduce_parts(float* __restrict__ P) {
    const size_t n = (size_t)B_ * T_ * H_;
    size_t i = ((size_t)blockIdx.x * 256 + threadIdx.x) * 4;
    if (i >= n) return;
    float4 a = *(float4*)(P + i);
#pragma unroll
    for (int s = 1; s < S; ++s) {
        float4 bq = *(const float4*)(P + (size_t)s * n + i);
        a.x += bq.x; a.y += bq.y; a.z += bq.z; a.w += bq.w;
    }
    *(float4*)(P + i) = a;
}

// ---------------------------------------------------------------------------
// Kernel 3: recurrent LIF scan. One wave per batch element, 8 neurons/lane.
// Phase 1 (serial in t): spike list compacted in LDS via ballot+prefix
// (wave-lockstep, zero barriers); recurrent gather in batches of 8 spikes =
// 64 loads in flight, ONE L2 round-trip per batch (vs per-spike before).
// Output work deferred: ballot masks recorded to LDS (16 KB).
// Phase 2: i2[t][o] computed in parallel over t, then an 11-lane relu-scan.
// ---------------------------------------------------------------------------
__global__ __launch_bounds__(64) void snn_rec(const float* __restrict__ I1,
                                              const float* __restrict__ wrT,
                                              const float* __restrict__ w2,
                                              float* __restrict__ out) {
    const int b = blockIdx.x;
    const int L = threadIdx.x;

    __shared__ int                smask_lo[T_ * 8];     // ballot masks, split
    __shared__ int                smask_hi[T_ * 8];     //  into 2x4KB... (8KB+8KB)
    __shared__ int                slist[2][H_];         // compacted spike lists
    __shared__ float              w2t[H_ * 12];         // w2 transposed [j][o]
    __shared__ float              i2s[T_ * 12];         // per-step output currents

    const float* i1p = I1 + (size_t)b * T_ * H_ + L;

    float v1[8], pf[8];
#pragma unroll
    for (int r = 0; r < 8; ++r) { v1[r] = 0.f; pf[r] = i1p[r * 64]; }

    const unsigned long long below = (L == 0) ? 0ull : ((~0ull) >> (64 - L));
    int pcnt = 0;      // previous step's spike count (uniform)

    for (int t = 0; t < T_; ++t) {
        const int pb = t & 1;          // list built last step lives in [pb^1]... use explicit
        const int prev = pb ^ 1;       // (t even: prev=1 holds t-1's list; t=0: pcnt=0, unused)

        // racc starts from feedforward (pf consumed here; next pf issued below)
        float racc[8];
#pragma unroll
        for (int r = 0; r < 8; ++r) racc[r] = pf[r] - LEAK_;

        // batched recurrent gather: 8 spikes x 8 rows = 64 loads, one wait
        for (int base = 0; base < pcnt; base += 8) {
            int jj[8];
#pragma unroll
            for (int s = 0; s < 8; ++s) {
                int ii = base + s;
                if (ii > pcnt - 1) ii = pcnt - 1;
                jj[s] = slist[prev][ii];
            }
            float vv[8][8];
#pragma unroll
            for (int s = 0; s < 8; ++s) {
                const float* wj = wrT + (size_t)jj[s] * H_ + L;
#pragma unroll
                for (int r = 0; r < 8; ++r) vv[s][r] = wj[r * 64];
            }
#pragma unroll
            for (int s = 0; s < 8; ++s) {
                if (base + s < pcnt) {
#pragma unroll
                    for (int r = 0; r < 8; ++r) racc[r] += vv[s][r];
                }
            }
        }

        // membrane update, spike decision, subtractive reset, ballots
        unsigned long long mk[8];
#pragma unroll
        for (int r = 0; r < 8; ++r) {
            v1[r] += racc[r];
            bool sp = (v1[r] >= THRESH);
            mk[r] = __ballot(sp);
            if (sp) v1[r] -= THRESH;
        }

        // record masks for phase 2 (lane 0; values are wave-uniform)
        if (L == 0) {
#pragma unroll
            for (int r = 0; r < 8; ++r) {
                smask_lo[t * 8 + r] = (int)(mk[r] & 0xffffffffull);
                smask_hi[t * 8 + r] = (int)(mk[r] >> 32);
            }
        }

        // build current step's compacted list (ascending neuron index)
        int cb = 0;
#pragma unroll
        for (int r = 0; r < 8; ++r) {
            int pos = (int)__popcll(mk[r] & below);
            if ((mk[r] >> L) & 1ull) slist[pb][cb + pos] = (r << 6) + L;
            cb += (int)__popcll(mk[r]);
        }
        pcnt = cb;

        // prefetch next step's feedforward AFTER the gather issues: its
        // latency lands off the recurrence chain (consumed next step).
        const float* nx = i1p + (size_t)((t + 1 < T_) ? t + 1 : t) * H_;
#pragma unroll
        for (int r = 0; r < 8; ++r) pf[r] = nx[r * 64];
    }

    __syncthreads();

    // ---- phase 2: output neurons, fully off the recurrence ----
    // stage w2 transposed: w2t[j*12+o] = w2[o*H+j]
    for (int j = L; j < H_; j += 64) {
#pragma unroll
        for (int o = 0; o < O_; ++o) w2t[j * 12 + o] = w2[o * H_ + j];
    }
    __syncthreads();

    // i2[t][o] = sum over spiking j (ascending) of w2[o][j]; parallel over t
    for (int tt = L; tt < T_; tt += 64) {
        float s0 = 0.f, s1 = 0.f, s2 = 0.f, s3 = 0.f, s4 = 0.f, s5 = 0.f,
              s6 = 0.f, s7 = 0.f, s8 = 0.f, s9 = 0.f, s10 = 0.f;
#pragma unroll
        for (int r = 0; r < 8; ++r) {
            unsigned long long m =
                ((unsigned long long)(unsigned)smask_lo[tt * 8 + r]) |
                (((unsigned long long)(unsigned)smask_hi[tt * 8 + r]) << 32);
            while (m) {
                int j = (r << 6) + __builtin_ctzll(m);
                m &= m - 1;
                const float* wp = &w2t[j * 12];
                s0 += wp[0]; s1 += wp[1]; s2 += wp[2]; s3 += wp[3];
                s4 += wp[4]; s5 += wp[5]; s6 += wp[6]; s7 += wp[7];
                s8 += wp[8]; s9 += wp[9]; s10 += wp[10];
            }
        }
        float* ip = &i2s[tt * 12];
        ip[0] = s0; ip[1] = s1; ip[2] = s2; ip[3] = s3; ip[4] = s4;
        ip[5] = s5; ip[6] = s6; ip[7] = s7; ip[8] = s8; ip[9] = s9; ip[10] = s10;
    }
    __syncthreads();

    // relu-scan over t for each output neuron (11 lanes)
    if (L < O_) {
        float v2 = 0.f, osum = 0.f;
        for (int t = 0; t < T_; ++t) {
            v2 = v2 + i2s[t * 12 + L] - OLEAK_;
            v2 = v2 > 0.f ? v2 : 0.f;
            osum += v2;
        }
        out[b * O_ + L] = osum * (1.0f / (float)T_);
    }
}

// ---------------------------------------------------------------------------
extern "C" void kernel_launch(void* const* d_in, const int* in_sizes, int n_in,
                              void* d_out, int out_size, void* d_ws, size_t ws_size,
                              hipStream_t stream) {
    const float* x     = (const float*)d_in[0];   // (B,T,C)
    const float* w1    = (const float*)d_in[1];   // (H,C)
    const float* w_rec = (const float*)d_in[2];   // (H,H)
    const float* w2    = (const float*)d_in[3];   // (O,H)
    float* out = (float*)d_out;                   // (B,O)

    const size_t PART = (size_t)B_ * T_ * H_ * sizeof(float);   // 32 MB
    const size_t WRT  = (size_t)H_ * H_ * sizeof(float);        // 1 MB

    int S = 1;
    if (ws_size >= 4 * PART + WRT) S = 4;
    else if (ws_size >= 2 * PART + WRT) S = 2;

    float* P   = (float*)d_ws;                      // I1 aliases P0 after reduce
    float* wrT = (float*)((char*)d_ws + (size_t)S * PART);

    transpose_wrec<<<dim3(H_ / 32, H_ / 32), dim3(32, 8), 0, stream>>>(w_rec, wrT);

    dim3 ggrid(H_ / BN, (B_ * T_) / BM, S);
    const int rblocks = (int)(((size_t)B_ * T_ * H_ / 4 + 255) / 256);
    switch (S) {
        case 4:
            gemm_ff<4><<<ggrid, dim3(128), 0, stream>>>(x, w1, P);
            reduce_parts<4><<<dim3(rblocks), dim3(256), 0, stream>>>(P);
            break;
        case 2:
            gemm_ff<2><<<ggrid, dim3(128), 0, stream>>>(x, w1, P);
            reduce_parts<2><<<dim3(rblocks), dim3(256), 0, stream>>>(P);
            break;
        default:
            gemm_ff<1><<<ggrid, dim3(128), 0, stream>>>(x, w1, P);
            break;
    }
    snn_rec<<<dim3(B_), dim3(64), 0, stream>>>(P, wrT, w2, out);
}